// Round 1
// baseline (209.285 us; speedup 1.0000x reference)
//
#include <hip/hip_runtime.h>
#include <hip/hip_bf16.h>
#include <math.h>

// Problem constants (fixed by setup_inputs)
#define B_  2
#define H_  3072
#define W_  4096
#define HH_ 1536           // H/2 (per-channel height)
#define WW_ 2048           // W/2 (per-channel width)
#define NCH 8              // B*4 channels
#define NROW (NCH*HH_)     // 12288 channel-rows

// ---------- order-preserving float <-> uint key ----------
__device__ __forceinline__ unsigned fkey(float x) {
  unsigned u = __float_as_uint(x);
  // nonneg: u | 0x80000000 ; neg: ~u  (ascending uint == ascending float)
  return u ^ (unsigned)((((int)u) >> 31) | 0x80000000);
}
__device__ __forceinline__ float funkey(unsigned k) {
  unsigned u = (k & 0x80000000u) ? (k ^ 0x80000000u) : ~k;
  return __uint_as_float(u);
}

// ---------- exact k-th smallest (0-indexed) across one wave ----------
// Each lane holds N values; total n = 64*N. Returns the exact key of
// sorted[k0] via 32-round MSB-first bisection; counts use ballot+popcount
// (uniform across lanes, no LDS, no barriers).
template<int N>
__device__ __forceinline__ unsigned bisect_kth(const unsigned* u, int k0) {
  unsigned p = 0u;
  for (int bit = 31; bit >= 0; --bit) {
    unsigned t = p | (1u << bit);
    int c = 0;
    #pragma unroll
    for (int i = 0; i < N; ++i)
      c += __popcll(__ballot(u[i] < t));
    if (c <= k0) p = t;   // kth value >= t -> keep this bit set
  }
  return p;
}

// ---------- pass A: per-channel-row median + sum|x| + sum x^2 + max|x| ----
// One wave per raw row (handles the 2 channels interleaved in that row).
__global__ __launch_bounds__(256) void k_rowstats(
    const float* __restrict__ raw,
    float* __restrict__ rowmed, float* __restrict__ rowsa,
    float* __restrict__ rowsq,  float* __restrict__ rowmx) {
  const int wave = threadIdx.x >> 6, lane = threadIdx.x & 63;
  const int g = blockIdx.x * 4 + wave;           // 0 .. 2*H-1 raw rows
  const int b = g / (HH_ * 2);
  const int rem = g - b * (HH_ * 2);
  const int y = rem >> 1, cp = rem & 1;          // channel-row y, raw-row parity
  const float4* rowp = (const float4*)(raw + ((size_t)b * H_ + (2 * y + cp)) * (size_t)W_);

  unsigned ue[32], uo[32];                       // even-col / odd-col channel values
  float sa_e = 0.f, sa_o = 0.f, sq_e = 0.f, sq_o = 0.f, mx_e = 0.f, mx_o = 0.f;
  #pragma unroll
  for (int i = 0; i < 16; ++i) {
    float4 v = rowp[lane + 64 * i];              // fully coalesced, 1KB/instr
    ue[2 * i] = fkey(v.x); ue[2 * i + 1] = fkey(v.z);
    uo[2 * i] = fkey(v.y); uo[2 * i + 1] = fkey(v.w);
    float ax = fabsf(v.x), ay = fabsf(v.y), az = fabsf(v.z), aw = fabsf(v.w);
    sa_e += ax + az;  sa_o += ay + aw;
    sq_e += v.x * v.x + v.z * v.z;  sq_o += v.y * v.y + v.w * v.w;
    mx_e = fmaxf(mx_e, fmaxf(ax, az));  mx_o = fmaxf(mx_o, fmaxf(ay, aw));
  }
  #pragma unroll
  for (int off = 32; off; off >>= 1) {
    sa_e += __shfl_xor(sa_e, off);  sa_o += __shfl_xor(sa_o, off);
    sq_e += __shfl_xor(sq_e, off);  sq_o += __shfl_xor(sq_o, off);
    mx_e = fmaxf(mx_e, __shfl_xor(mx_e, off));
    mx_o = fmaxf(mx_o, __shfl_xor(mx_o, off));
  }
  unsigned pe = bisect_kth<32>(ue, 1023);        // lower median of 2048
  unsigned po = bisect_kth<32>(uo, 1023);
  if (lane == 0) {
    const int re = (b * 4 + 2 * cp) * HH_ + y;   // channel c=2cp
    const int ro = re + HH_;                     // channel c=2cp+1
    rowmed[re] = funkey(pe);  rowmed[ro] = funkey(po);
    rowsa[re] = sa_e;  rowsa[ro] = sa_o;
    rowsq[re] = sq_e;  rowsq[ro] = sq_o;
    rowmx[re] = mx_e;  rowmx[ro] = mx_o;
  }
}

// ---------- reduce A: per-channel median-of-row-medians + mean/max feats ----
__global__ __launch_bounds__(64) void k_chanA(
    const float* __restrict__ rowmed, const float* __restrict__ rowsa,
    const float* __restrict__ rowsq,  const float* __restrict__ rowmx,
    float* __restrict__ med, float* __restrict__ feats) {
  const int ch = blockIdx.x, lane = threadIdx.x;
  unsigned u[24];
  float sa = 0.f, sq = 0.f, mx = 0.f;
  #pragma unroll
  for (int j = 0; j < 24; ++j) {
    int i = ch * HH_ + lane + 64 * j;
    u[j] = fkey(rowmed[i]);
    sa += rowsa[i];  sq += rowsq[i];  mx = fmaxf(mx, rowmx[i]);
  }
  unsigned p = bisect_kth<24>(u, 767);           // lower median of 1536
  #pragma unroll
  for (int off = 32; off; off >>= 1) {
    sa += __shfl_xor(sa, off);  sq += __shfl_xor(sq, off);
    mx = fmaxf(mx, __shfl_xor(mx, off));
  }
  if (lane == 0) {
    med[ch] = funkey(p);
    const float inv = 1.f / (float)(HH_ * WW_);
    const int b = ch >> 2, c = ch & 3;
    feats[b * 16 + c]      = sa * inv;           // mean_abs
    feats[b * 16 + 4 + c]  = sq * inv;           // mean_r2
    feats[b * 16 + 12 + c] = mx;                 // max_abs
  }
}

// ---------- pass B: per-row median of |x - med(channel)| ----------
__global__ __launch_bounds__(256) void k_madrows(
    const float* __restrict__ raw, const float* __restrict__ med,
    float* __restrict__ rowmad) {
  const int wave = threadIdx.x >> 6, lane = threadIdx.x & 63;
  const int g = blockIdx.x * 4 + wave;
  const int b = g / (HH_ * 2);
  const int rem = g - b * (HH_ * 2);
  const int y = rem >> 1, cp = rem & 1;
  const float4* rowp = (const float4*)(raw + ((size_t)b * H_ + (2 * y + cp)) * (size_t)W_);
  const float me = med[b * 4 + 2 * cp];
  const float mo = med[b * 4 + 2 * cp + 1];

  unsigned ue[32], uo[32];
  #pragma unroll
  for (int i = 0; i < 16; ++i) {
    float4 v = rowp[lane + 64 * i];
    ue[2 * i]     = fkey(fabsf(v.x - me));
    ue[2 * i + 1] = fkey(fabsf(v.z - me));
    uo[2 * i]     = fkey(fabsf(v.y - mo));
    uo[2 * i + 1] = fkey(fabsf(v.w - mo));
  }
  unsigned pe = bisect_kth<32>(ue, 1023);
  unsigned po = bisect_kth<32>(uo, 1023);
  if (lane == 0) {
    const int re = (b * 4 + 2 * cp) * HH_ + y;
    rowmad[re] = funkey(pe);
    rowmad[re + HH_] = funkey(po);
  }
}

// ---------- reduce B: channel MAD -> mad_vars feature ----------
__global__ __launch_bounds__(64) void k_chanB(
    const float* __restrict__ rowmad, float* __restrict__ feats) {
  const int ch = blockIdx.x, lane = threadIdx.x;
  unsigned u[24];
  #pragma unroll
  for (int j = 0; j < 24; ++j)
    u[j] = fkey(rowmad[ch * HH_ + lane + 64 * j]);
  unsigned p = bisect_kth<24>(u, 767);
  if (lane == 0) {
    float mad = funkey(p);
    float sigma = 1.4826f * mad;
    const int b = ch >> 2, c = ch & 3;
    feats[b * 16 + 8 + c] = sigma * sigma + 1e-8f;  // mad_vars
  }
}

// ---------- tiny MLPs ----------
__device__ __forceinline__ float spf(float x) {      // jax.nn.softplus = logaddexp(x,0)
  return fmaxf(x, 0.f) + log1pf(expf(-fabsf(x)));
}

__global__ __launch_bounds__(256) void k_mlp(
    const float* __restrict__ feats,
    const float* __restrict__ W1e, const float* __restrict__ b1e,
    const float* __restrict__ W2e, const float* __restrict__ b2e,
    const float* __restrict__ W1u, const float* __restrict__ b1u,
    const float* __restrict__ W2u, const float* __restrict__ b2u,
    const float* __restrict__ gainp, float* __restrict__ out) {
  __shared__ float xs[2][16];
  __shared__ float he[2][128];
  __shared__ float hu[2][128];
  const int t = threadIdx.x;
  if (t < 32) xs[t >> 4][t & 15] = feats[t];
  __syncthreads();
  {
    const int b = t >> 7, j = t & 127;
    float se = b1e[j], su = b1u[j];
    #pragma unroll
    for (int k = 0; k < 16; ++k) {
      float xv = xs[b][k];
      se += xv * spf(W1e[j * 16 + k]);
      su += xv * spf(W1u[j * 16 + k]);
    }
    he[b][j] = spf(se);
    hu[b][j] = spf(su);
  }
  __syncthreads();
  if (t < 128) {
    const int b = t >> 6, d = t & 63;
    float s = b2e[d];
    for (int j = 0; j < 128; ++j) s += he[b][j] * spf(W2e[d * 128 + j]);
    out[b * 64 + d] = gainp[0] * s;              // emb
  } else if (t < 130) {
    const int b = t - 128;
    float s = b2u[0];
    for (int j = 0; j < 128; ++j) s += hu[b][j] * spf(W2u[j]);
    out[128 + b] = s;                            // u
  }
}

extern "C" void kernel_launch(void* const* d_in, const int* in_sizes, int n_in,
                              void* d_out, int out_size, void* d_ws, size_t ws_size,
                              hipStream_t stream) {
  const float* raw  = (const float*)d_in[0];
  const float* W1e  = (const float*)d_in[1];
  const float* b1e  = (const float*)d_in[2];
  const float* W2e  = (const float*)d_in[3];
  const float* b2e  = (const float*)d_in[4];
  const float* W1u  = (const float*)d_in[5];
  const float* b1u  = (const float*)d_in[6];
  const float* W2u  = (const float*)d_in[7];
  const float* b2u  = (const float*)d_in[8];
  const float* gain = (const float*)d_in[9];
  float* out = (float*)d_out;

  // ws layout (floats): needs 61480 floats = ~246 KB
  float* ws     = (float*)d_ws;
  float* rowmed = ws;                  // 12288
  float* rowsa  = ws + NROW;           // 12288
  float* rowsq  = ws + 2 * NROW;       // 12288
  float* rowmx  = ws + 3 * NROW;       // 12288
  float* med    = ws + 4 * NROW;       // 8
  float* rowmad = ws + 4 * NROW + 8;   // 12288
  float* feats  = ws + 5 * NROW + 8;   // 32

  const int blocksA = (2 * H_) / 4;    // 1536 blocks, 4 waves (raw rows) each

  k_rowstats<<<blocksA, 256, 0, stream>>>(raw, rowmed, rowsa, rowsq, rowmx);
  k_chanA<<<NCH, 64, 0, stream>>>(rowmed, rowsa, rowsq, rowmx, med, feats);
  k_madrows<<<blocksA, 256, 0, stream>>>(raw, med, rowmad);
  k_chanB<<<NCH, 64, 0, stream>>>(rowmad, feats);
  k_mlp<<<1, 256, 0, stream>>>(feats, W1e, b1e, W2e, b2e, W1u, b1u, W2u, b2u, gain, out);
}

// Round 2
// 137.443 us; speedup vs baseline: 1.5227x; 1.5227x over previous
//
#include <hip/hip_runtime.h>
#include <hip/hip_bf16.h>
#include <math.h>

// Problem constants (fixed by setup_inputs)
#define B_  2
#define H_  3072
#define W_  4096
#define HH_ 1536           // H/2 (per-channel height)
#define WW_ 2048           // W/2 (per-channel width)
#define NCH 8              // B*4 channels
#define NROW (NCH*HH_)     // 12288 channel-rows

// ---------- order-preserving float <-> uint key ----------
__device__ __forceinline__ unsigned fkey(float x) {
  unsigned u = __float_as_uint(x);
  return u ^ (unsigned)((((int)u) >> 31) | 0x80000000);
}
__device__ __forceinline__ float funkey(unsigned k) {
  unsigned u = (k & 0x80000000u) ? (k & 0x7FFFFFFFu) : ~k;
  return __uint_as_float(u);
}

// ---------- wave-wide int sum (all lanes get total) ----------
__device__ __forceinline__ int wsum(int c) {
  #pragma unroll
  for (int off = 32; off; off >>= 1) c += __shfl_xor(c, off);
  return c;
}

// ---------- in-register 32x32 bit transpose (Hacker's Delight) ----------
// After this, the word at index (31-b) holds bit b of key i at bit pos (31-i).
// The element permutation i -> 31-i is consistent across planes (harmless for
// rank selection, which is order-agnostic).
__device__ __forceinline__ void transpose32(unsigned (&A)[32]) {
  const unsigned MASKS[5] = {0x0000FFFFu, 0x00FF00FFu, 0x0F0F0F0Fu,
                             0x33333333u, 0x55555555u};
  #pragma unroll
  for (int s = 0; s < 5; ++s) {
    const int j = 16 >> s;
    const unsigned m = MASKS[s];
    #pragma unroll
    for (int k = 0; k < 32; ++k) {
      if ((k & j) == 0) {
        unsigned t = (A[k] ^ (A[k + j] >> j)) & m;
        A[k]     ^= t;
        A[k + j] ^= (t << j);
      }
    }
  }
}

// ---------- exact rank-kk (0-indexed ascending) of 64*32 keys ----------
// A = bit-planes from transpose32. Radix select, MSB-first from bit HI.
// res carries pre-decided high bits (e.g. 0x80000000 when all keys >= that).
template<int HI>
__device__ __forceinline__ unsigned plane_select(const unsigned (&A)[32],
                                                 int kk, unsigned res) {
  unsigned act = 0xFFFFFFFFu;
  #pragma unroll
  for (int b = HI; b >= 0; --b) {
    const unsigned pl = A[31 - b];      // compile-time index (loop unrolled)
    unsigned zeros = act & ~pl;
    int c = wsum(__popc(zeros));        // uniform across lanes after wsum
    if (kk < c) {
      act = zeros;                      // kth element has bit b = 0
    } else {
      act &= pl;                        // bit b = 1
      kk -= c;
      res |= (1u << b);
    }
  }
  return res;
}

// ---------- pass A: one wave per channel-row ----------
// Block = 4 waves = 2 raw rows x 2 col-parities. Parity waves share the raw
// row's cache lines (L1 serves the second reader).
__global__ __launch_bounds__(256) void k_rowstats(
    const float* __restrict__ raw,
    float* __restrict__ rowmed, float* __restrict__ rowsa,
    float* __restrict__ rowsq,  float* __restrict__ rowmx) {
  const int wave = threadIdx.x >> 6, lane = threadIdx.x & 63;
  const int rg  = blockIdx.x * 2 + (wave >> 1);  // raw row 0..B*H-1
  const int par = wave & 1;                      // column parity
  const int b   = rg / H_;
  const int row = rg - b * H_;
  const int y = row >> 1, cp = row & 1;
  const int c = 2 * cp + par;                    // RGGB channel
  const float4* rowp = (const float4*)(raw + (size_t)rg * W_);

  unsigned A[32];
  float sa = 0.f, sq = 0.f, mx = 0.f;
  #pragma unroll
  for (int i = 0; i < 16; ++i) {
    float4 v = rowp[i * 64 + lane];              // coalesced 16B/lane
    float s0 = par ? v.y : v.x;
    float s1 = par ? v.w : v.z;
    A[2 * i]     = fkey(s0);
    A[2 * i + 1] = fkey(s1);
    float a0 = fabsf(s0), a1 = fabsf(s1);
    sa += a0 + a1;
    sq += s0 * s0 + s1 * s1;
    mx = fmaxf(mx, fmaxf(a0, a1));
  }
  transpose32(A);
  unsigned res = plane_select<31>(A, 1023, 0u);  // lower median of 2048
  #pragma unroll
  for (int off = 32; off; off >>= 1) {
    sa += __shfl_xor(sa, off);
    sq += __shfl_xor(sq, off);
    mx = fmaxf(mx, __shfl_xor(mx, off));
  }
  if (lane == 0) {
    const int cr = (b * 4 + c) * HH_ + y;
    rowmed[cr] = funkey(res);
    rowsa[cr] = sa;  rowsq[cr] = sq;  rowmx[cr] = mx;
  }
}

// ---------- reduce A: per-channel median-of-medians + mean/max feats ----------
__global__ __launch_bounds__(64) void k_chanA(
    const float* __restrict__ rowmed, const float* __restrict__ rowsa,
    const float* __restrict__ rowsq,  const float* __restrict__ rowmx,
    float* __restrict__ med, float* __restrict__ feats) {
  const int ch = blockIdx.x, lane = threadIdx.x;
  unsigned A[32];
  float sa = 0.f, sq = 0.f, mx = 0.f;
  #pragma unroll
  for (int j = 0; j < 24; ++j) {
    int i = ch * HH_ + j * 64 + lane;
    A[j] = fkey(rowmed[i]);
    sa += rowsa[i];  sq += rowsq[i];  mx = fmaxf(mx, rowmx[i]);
  }
  #pragma unroll
  for (int j = 24; j < 32; ++j) A[j] = 0xFFFFFFFFu;  // +inf pad (rank 767 < 1536)
  transpose32(A);
  unsigned res = plane_select<31>(A, 767, 0u);       // lower median of 1536
  #pragma unroll
  for (int off = 32; off; off >>= 1) {
    sa += __shfl_xor(sa, off);
    sq += __shfl_xor(sq, off);
    mx = fmaxf(mx, __shfl_xor(mx, off));
  }
  if (lane == 0) {
    med[ch] = funkey(res);
    const float inv = 1.f / (float)(HH_ * WW_);
    const int b = ch >> 2, c = ch & 3;
    feats[b * 16 + c]      = sa * inv;   // mean_abs
    feats[b * 16 + 4 + c]  = sq * inv;   // mean_r2
    feats[b * 16 + 12 + c] = mx;         // max_abs
  }
}

// ---------- pass B: per-row median of |x - med(channel)| ----------
__global__ __launch_bounds__(256) void k_madrows(
    const float* __restrict__ raw, const float* __restrict__ med,
    float* __restrict__ rowmad) {
  const int wave = threadIdx.x >> 6, lane = threadIdx.x & 63;
  const int rg  = blockIdx.x * 2 + (wave >> 1);
  const int par = wave & 1;
  const int b   = rg / H_;
  const int row = rg - b * H_;
  const int y = row >> 1, cp = row & 1;
  const int c = 2 * cp + par;
  const float m = med[b * 4 + c];
  const float4* rowp = (const float4*)(raw + (size_t)rg * W_);

  unsigned A[32];
  #pragma unroll
  for (int i = 0; i < 16; ++i) {
    float4 v = rowp[i * 64 + lane];
    float s0 = par ? v.y : v.x;
    float s1 = par ? v.w : v.z;
    A[2 * i]     = fkey(fabsf(s0 - m));
    A[2 * i + 1] = fkey(fabsf(s1 - m));
  }
  transpose32(A);
  // keys are all nonneg -> bit 31 is always 1: skip that round.
  unsigned res = plane_select<30>(A, 1023, 0x80000000u);
  if (lane == 0) {
    const int cr = (b * 4 + c) * HH_ + y;
    rowmad[cr] = funkey(res);
  }
}

// ---------- reduce B: channel MAD -> mad_vars feature ----------
__global__ __launch_bounds__(64) void k_chanB(
    const float* __restrict__ rowmad, float* __restrict__ feats) {
  const int ch = blockIdx.x, lane = threadIdx.x;
  unsigned A[32];
  #pragma unroll
  for (int j = 0; j < 24; ++j)
    A[j] = fkey(rowmad[ch * HH_ + j * 64 + lane]);
  #pragma unroll
  for (int j = 24; j < 32; ++j) A[j] = 0xFFFFFFFFu;
  transpose32(A);
  unsigned res = plane_select<30>(A, 767, 0x80000000u);  // nonneg keys
  if (lane == 0) {
    float mad = funkey(res);
    float sigma = 1.4826f * mad;
    const int b = ch >> 2, c = ch & 3;
    feats[b * 16 + 8 + c] = sigma * sigma + 1e-8f;   // mad_vars
  }
}

// ---------- tiny MLPs ----------
__device__ __forceinline__ float spf(float x) {      // jax.nn.softplus
  return fmaxf(x, 0.f) + log1pf(expf(-fabsf(x)));
}

__global__ __launch_bounds__(256) void k_mlp(
    const float* __restrict__ feats,
    const float* __restrict__ W1e, const float* __restrict__ b1e,
    const float* __restrict__ W2e, const float* __restrict__ b2e,
    const float* __restrict__ W1u, const float* __restrict__ b1u,
    const float* __restrict__ W2u, const float* __restrict__ b2u,
    const float* __restrict__ gainp, float* __restrict__ out) {
  __shared__ float xs[2][16];
  __shared__ float he[2][128];
  __shared__ float hu[2][128];
  const int t = threadIdx.x;
  if (t < 32) xs[t >> 4][t & 15] = feats[t];
  __syncthreads();
  {
    const int b = t >> 7, j = t & 127;
    float se = b1e[j], su = b1u[j];
    #pragma unroll
    for (int k = 0; k < 16; ++k) {
      float xv = xs[b][k];
      se += xv * spf(W1e[j * 16 + k]);
      su += xv * spf(W1u[j * 16 + k]);
    }
    he[b][j] = spf(se);
    hu[b][j] = spf(su);
  }
  __syncthreads();
  if (t < 128) {
    const int b = t >> 6, d = t & 63;
    float s = b2e[d];
    for (int j = 0; j < 128; ++j) s += he[b][j] * spf(W2e[d * 128 + j]);
    out[b * 64 + d] = gainp[0] * s;              // emb
  } else if (t < 130) {
    const int b = t - 128;
    float s = b2u[0];
    for (int j = 0; j < 128; ++j) s += hu[b][j] * spf(W2u[j]);
    out[128 + b] = s;                            // u
  }
}

extern "C" void kernel_launch(void* const* d_in, const int* in_sizes, int n_in,
                              void* d_out, int out_size, void* d_ws, size_t ws_size,
                              hipStream_t stream) {
  const float* raw  = (const float*)d_in[0];
  const float* W1e  = (const float*)d_in[1];
  const float* b1e  = (const float*)d_in[2];
  const float* W2e  = (const float*)d_in[3];
  const float* b2e  = (const float*)d_in[4];
  const float* W1u  = (const float*)d_in[5];
  const float* b1u  = (const float*)d_in[6];
  const float* W2u  = (const float*)d_in[7];
  const float* b2u  = (const float*)d_in[8];
  const float* gain = (const float*)d_in[9];
  float* out = (float*)d_out;

  float* ws     = (float*)d_ws;
  float* rowmed = ws;                  // 12288
  float* rowsa  = ws + NROW;           // 12288
  float* rowsq  = ws + 2 * NROW;       // 12288
  float* rowmx  = ws + 3 * NROW;       // 12288
  float* med    = ws + 4 * NROW;       // 8
  float* rowmad = ws + 4 * NROW + 8;   // 12288
  float* feats  = ws + 5 * NROW + 8;   // 32

  const int blocks = (B_ * H_) / 2;    // 3072 blocks, 4 waves (2 rows x 2 par)

  k_rowstats<<<blocks, 256, 0, stream>>>(raw, rowmed, rowsa, rowsq, rowmx);
  k_chanA<<<NCH, 64, 0, stream>>>(rowmed, rowsa, rowsq, rowmx, med, feats);
  k_madrows<<<blocks, 256, 0, stream>>>(raw, med, rowmad);
  k_chanB<<<NCH, 64, 0, stream>>>(rowmad, feats);
  k_mlp<<<1, 256, 0, stream>>>(feats, W1e, b1e, W2e, b2e, W1u, b1u, W2u, b2u, gain, out);
}

// Round 4
// 85.406 us; speedup vs baseline: 2.4505x; 1.6093x over previous
//
#include <hip/hip_runtime.h>
#include <hip/hip_bf16.h>
#include <math.h>

// Problem constants (fixed by setup_inputs)
#define B_  2
#define H_  3072
#define W_  4096
#define HH_ 1536           // H/2 (per-channel height)
#define WW_ 2048           // W/2 (per-channel width)
#define NCH 8              // B*4 channels
#define NROW (NCH*HH_)     // 12288 channel-rows

// ---------- order-preserving float <-> uint key ----------
__device__ __forceinline__ unsigned fkey(float x) {
  unsigned u = __float_as_uint(x);
  return u ^ (unsigned)((((int)u) >> 31) | 0x80000000);
}
__device__ __forceinline__ float funkey(unsigned k) {
  unsigned u = (k & 0x80000000u) ? (k & 0x7FFFFFFFu) : ~k;
  return __uint_as_float(u);
}

// ---------- DPP helpers (ctrl/rmask must be compile-time constants) ----------
template<int CTRL, int RMASK>
__device__ __forceinline__ int dppi(int x) {
  return __builtin_amdgcn_update_dpp(0, x, CTRL, RMASK, 0xF, false);
}
template<int CTRL, int RMASK>
__device__ __forceinline__ float dppf(float x) {
  return __int_as_float(
      __builtin_amdgcn_update_dpp(0, __float_as_int(x), CTRL, RMASK, 0xF, false));
}

// Wave64 sum via DPP (LLVM atomic-optimizer sequence):
// row_shr:1/2/4/8 builds 16-lane suffix sums; row_bcast:15/31 merge rows.
// Total lands in lane 63; readlane makes it uniform (SGPR).
__device__ __forceinline__ int wave_sum64(int x) {
  x += dppi<0x111, 0xF>(x);   // row_shr:1
  x += dppi<0x112, 0xF>(x);   // row_shr:2
  x += dppi<0x114, 0xF>(x);   // row_shr:4
  x += dppi<0x118, 0xF>(x);   // row_shr:8
  x += dppi<0x142, 0xA>(x);   // row_bcast:15 -> rows 1,3
  x += dppi<0x143, 0xC>(x);   // row_bcast:31 -> rows 2,3
  return __builtin_amdgcn_readlane(x, 63);
}
// sum/sum/max of nonneg floats; results valid in lane 63.
// (bound-off lanes contribute 0, safe for nonneg sums and max)
__device__ __forceinline__ void wave_red3(float& sa, float& sq, float& mx) {
  sa += dppf<0x111, 0xF>(sa); sq += dppf<0x111, 0xF>(sq); mx = fmaxf(mx, dppf<0x111, 0xF>(mx));
  sa += dppf<0x112, 0xF>(sa); sq += dppf<0x112, 0xF>(sq); mx = fmaxf(mx, dppf<0x112, 0xF>(mx));
  sa += dppf<0x114, 0xF>(sa); sq += dppf<0x114, 0xF>(sq); mx = fmaxf(mx, dppf<0x114, 0xF>(mx));
  sa += dppf<0x118, 0xF>(sa); sq += dppf<0x118, 0xF>(sq); mx = fmaxf(mx, dppf<0x118, 0xF>(mx));
  sa += dppf<0x142, 0xA>(sa); sq += dppf<0x142, 0xA>(sq); mx = fmaxf(mx, dppf<0x142, 0xA>(mx));
  sa += dppf<0x143, 0xC>(sa); sq += dppf<0x143, 0xC>(sq); mx = fmaxf(mx, dppf<0x143, 0xC>(mx));
}

// ---------- in-register 32x32 bit transpose (Hacker's Delight) ----------
// Word (31-b) afterwards holds bit b of key i at bit pos (31-i). The element
// permutation is harmless for rank selection (order-agnostic).
__device__ __forceinline__ void transpose32(unsigned (&A)[32]) {
  const unsigned MASKS[5] = {0x0000FFFFu, 0x00FF00FFu, 0x0F0F0F0Fu,
                             0x33333333u, 0x55555555u};
  #pragma unroll
  for (int s = 0; s < 5; ++s) {
    const int j = 16 >> s;
    const unsigned m = MASKS[s];
    #pragma unroll
    for (int k = 0; k < 32; ++k) {
      if ((k & j) == 0) {
        unsigned t = (A[k] ^ (A[k + j] >> j)) & m;
        A[k]     ^= t;
        A[k + j] ^= (t << j);
      }
    }
  }
}

// ---------- exact rank-kk (0-indexed ascending) of 64*32 keys ----------
// Radix select on bit-planes, MSB-first from bit HI. res carries pre-decided
// high bits. Per round: 2 VALU + DPP reduce + uniform scalar branch.
template<int HI>
__device__ __forceinline__ unsigned plane_select(const unsigned (&A)[32],
                                                 int kk, unsigned res) {
  unsigned act = 0xFFFFFFFFu;
  #pragma unroll
  for (int b = HI; b >= 0; --b) {
    const unsigned pl = A[31 - b];
    unsigned zeros = act & ~pl;
    int c = wave_sum64(__popc(zeros));
    if (kk < c) {
      act = zeros;                      // kth element has bit b = 0
    } else {
      act &= pl;                        // bit b = 1
      kk -= c;
      res |= (1u << b);
    }
  }
  return res;
}

// ---------- pass A: one wave per channel-row ----------
// Block = 4 waves = 2 raw rows x 2 col-parities (parity waves share lines).
__global__ __launch_bounds__(256) void k_rowstats(
    const float* __restrict__ raw,
    float* __restrict__ rowmed, float* __restrict__ rowsa,
    float* __restrict__ rowsq,  float* __restrict__ rowmx) {
  const int wave = threadIdx.x >> 6, lane = threadIdx.x & 63;
  const int rg  = blockIdx.x * 2 + (wave >> 1);  // raw row 0..B*H-1
  const int par = wave & 1;                      // column parity
  const int b   = rg / H_;
  const int row = rg - b * H_;
  const int y = row >> 1, cp = row & 1;
  const int c = 2 * cp + par;                    // RGGB channel
  const float4* rowp = (const float4*)(raw + (size_t)rg * W_);

  unsigned A[32];
  float sa = 0.f, sq = 0.f, mx = 0.f;
  #pragma unroll
  for (int i = 0; i < 16; ++i) {
    float4 v = rowp[i * 64 + lane];              // coalesced 16B/lane
    float s0 = par ? v.y : v.x;
    float s1 = par ? v.w : v.z;
    A[2 * i]     = fkey(s0);
    A[2 * i + 1] = fkey(s1);
    float a0 = fabsf(s0), a1 = fabsf(s1);
    sa += a0 + a1;
    sq += s0 * s0 + s1 * s1;
    mx = fmaxf(mx, fmaxf(a0, a1));
  }
  transpose32(A);
  unsigned res = plane_select<31>(A, 1023, 0u);  // lower median of 2048
  wave_red3(sa, sq, mx);
  if (lane == 63) {
    const int cr = (b * 4 + c) * HH_ + y;
    rowmed[cr] = funkey(res);
    rowsa[cr] = sa;  rowsq[cr] = sq;  rowmx[cr] = mx;
  }
}

// ---------- reduce A: per-channel median-of-medians + mean/max feats ----------
__global__ __launch_bounds__(64) void k_chanA(
    const float* __restrict__ rowmed, const float* __restrict__ rowsa,
    const float* __restrict__ rowsq,  const float* __restrict__ rowmx,
    float* __restrict__ med, float* __restrict__ feats) {
  const int ch = blockIdx.x, lane = threadIdx.x;
  unsigned A[32];
  float sa = 0.f, sq = 0.f, mx = 0.f;
  #pragma unroll
  for (int j = 0; j < 24; ++j) {
    int i = ch * HH_ + j * 64 + lane;
    A[j] = fkey(rowmed[i]);
    sa += rowsa[i];  sq += rowsq[i];  mx = fmaxf(mx, rowmx[i]);
  }
  #pragma unroll
  for (int j = 24; j < 32; ++j) A[j] = 0xFFFFFFFFu;  // +inf pad (rank 767 < 1536)
  transpose32(A);
  unsigned res = plane_select<31>(A, 767, 0u);       // lower median of 1536
  wave_red3(sa, sq, mx);
  if (lane == 63) {
    med[ch] = funkey(res);
    const float inv = 1.f / (float)(HH_ * WW_);
    const int b = ch >> 2, c = ch & 3;
    feats[b * 16 + c]      = sa * inv;   // mean_abs
    feats[b * 16 + 4 + c]  = sq * inv;   // mean_r2
    feats[b * 16 + 12 + c] = mx;         // max_abs
  }
}

// ---------- pass B: per-row median of |x - med(channel)| ----------
__global__ __launch_bounds__(256) void k_madrows(
    const float* __restrict__ raw, const float* __restrict__ med,
    float* __restrict__ rowmad) {
  const int wave = threadIdx.x >> 6, lane = threadIdx.x & 63;
  const int rg  = blockIdx.x * 2 + (wave >> 1);
  const int par = wave & 1;
  const int b   = rg / H_;
  const int row = rg - b * H_;
  const int y = row >> 1, cp = row & 1;
  const int c = 2 * cp + par;
  const float m = med[b * 4 + c];
  const float4* rowp = (const float4*)(raw + (size_t)rg * W_);

  unsigned A[32];
  #pragma unroll
  for (int i = 0; i < 16; ++i) {
    float4 v = rowp[i * 64 + lane];
    float s0 = par ? v.y : v.x;
    float s1 = par ? v.w : v.z;
    A[2 * i]     = fkey(fabsf(s0 - m));
    A[2 * i + 1] = fkey(fabsf(s1 - m));
  }
  transpose32(A);
  // keys all nonneg -> bit 31 always set: skip that round.
  unsigned res = plane_select<30>(A, 1023, 0x80000000u);
  if (lane == 0) {
    const int cr = (b * 4 + c) * HH_ + y;
    rowmad[cr] = funkey(res);
  }
}

// ---------- reduce B: channel MAD -> mad_vars feature ----------
__global__ __launch_bounds__(64) void k_chanB(
    const float* __restrict__ rowmad, float* __restrict__ feats) {
  const int ch = blockIdx.x, lane = threadIdx.x;
  unsigned A[32];
  #pragma unroll
  for (int j = 0; j < 24; ++j)
    A[j] = fkey(rowmad[ch * HH_ + j * 64 + lane]);
  #pragma unroll
  for (int j = 24; j < 32; ++j) A[j] = 0xFFFFFFFFu;
  transpose32(A);
  unsigned res = plane_select<30>(A, 767, 0x80000000u);  // nonneg keys
  if (lane == 0) {
    float mad = funkey(res);
    float sigma = 1.4826f * mad;
    const int b = ch >> 2, c = ch & 3;
    feats[b * 16 + 8 + c] = sigma * sigma + 1e-8f;   // mad_vars
  }
}

// ---------- tiny MLPs (fully parallel layer 2) ----------
__device__ __forceinline__ float spf(float x) {      // jax.nn.softplus
  return fmaxf(x, 0.f) + log1pf(expf(-fabsf(x)));
}

__global__ __launch_bounds__(256) void k_mlp(
    const float* __restrict__ feats,
    const float* __restrict__ W1e, const float* __restrict__ b1e,
    const float* __restrict__ W2e, const float* __restrict__ b2e,
    const float* __restrict__ W1u, const float* __restrict__ b1u,
    const float* __restrict__ W2u, const float* __restrict__ b2u,
    const float* __restrict__ gainp, float* __restrict__ out) {
  __shared__ float xs[2][16];
  __shared__ float he[2][128];
  __shared__ float hu[2][128];
  const int t = threadIdx.x;
  if (t < 32) xs[t >> 4][t & 15] = feats[t];
  __syncthreads();
  {  // layer 1: 2 batches x 128 hidden, one thread each; float4 weight loads
    const int b = t >> 7, j = t & 127;
    const float4* w1e = (const float4*)(W1e + j * 16);
    const float4* w1u = (const float4*)(W1u + j * 16);
    float se = b1e[j], su = b1u[j];
    #pragma unroll
    for (int q = 0; q < 4; ++q) {
      float4 we = w1e[q], wu = w1u[q];
      float x0 = xs[b][4 * q], x1 = xs[b][4 * q + 1];
      float x2 = xs[b][4 * q + 2], x3 = xs[b][4 * q + 3];
      se += x0 * spf(we.x) + x1 * spf(we.y) + x2 * spf(we.z) + x3 * spf(we.w);
      su += x0 * spf(wu.x) + x1 * spf(wu.y) + x2 * spf(wu.z) + x3 * spf(wu.w);
    }
    he[b][j] = spf(se);
    hu[b][j] = spf(su);
  }
  __syncthreads();
  {  // emb head: 128 (b,d) outputs x 2 threads (64 terms each, float4 loads)
    const int pair = t >> 1, half = t & 1;
    const int b = pair >> 6, d = pair & 63;
    const float4* w2 = (const float4*)(W2e + d * 128 + half * 64);
    float s = 0.f;
    #pragma unroll
    for (int q = 0; q < 16; ++q) {
      float4 w = w2[q];
      const int j = half * 64 + 4 * q;
      s += he[b][j]     * spf(w.x) + he[b][j + 1] * spf(w.y)
         + he[b][j + 2] * spf(w.z) + he[b][j + 3] * spf(w.w);
    }
    s += __shfl_xor(s, 1);
    if (half == 0) out[b * 64 + d] = gainp[0] * (s + b2e[d]);
  }
  if (t >= 192) {  // u head on wave 3: 2 batches x 32 lanes x 4 terms
    const int tt = t - 192, b = tt >> 5, l = tt & 31;
    float4 w = ((const float4*)W2u)[l];
    float s = hu[b][4 * l]     * spf(w.x) + hu[b][4 * l + 1] * spf(w.y)
            + hu[b][4 * l + 2] * spf(w.z) + hu[b][4 * l + 3] * spf(w.w);
    #pragma unroll
    for (int off = 1; off < 32; off <<= 1) s += __shfl_xor(s, off);
    if (l == 0) out[128 + b] = s + b2u[0];
  }
}

extern "C" void kernel_launch(void* const* d_in, const int* in_sizes, int n_in,
                              void* d_out, int out_size, void* d_ws, size_t ws_size,
                              hipStream_t stream) {
  const float* raw  = (const float*)d_in[0];
  const float* W1e  = (const float*)d_in[1];
  const float* b1e  = (const float*)d_in[2];
  const float* W2e  = (const float*)d_in[3];
  const float* b2e  = (const float*)d_in[4];
  const float* W1u  = (const float*)d_in[5];
  const float* b1u  = (const float*)d_in[6];
  const float* W2u  = (const float*)d_in[7];
  const float* b2u  = (const float*)d_in[8];
  const float* gain = (const float*)d_in[9];
  float* out = (float*)d_out;

  float* ws     = (float*)d_ws;
  float* rowmed = ws;                  // 12288
  float* rowsa  = ws + NROW;           // 12288
  float* rowsq  = ws + 2 * NROW;       // 12288
  float* rowmx  = ws + 3 * NROW;       // 12288
  float* med    = ws + 4 * NROW;       // 8
  float* rowmad = ws + 4 * NROW + 8;   // 12288
  float* feats  = ws + 5 * NROW + 8;   // 32

  const int blocks = (B_ * H_) / 2;    // 3072 blocks, 4 waves (2 rows x 2 par)

  k_rowstats<<<blocks, 256, 0, stream>>>(raw, rowmed, rowsa, rowsq, rowmx);
  k_chanA<<<NCH, 64, 0, stream>>>(rowmed, rowsa, rowsq, rowmx, med, feats);
  k_madrows<<<blocks, 256, 0, stream>>>(raw, med, rowmad);
  k_chanB<<<NCH, 64, 0, stream>>>(rowmad, feats);
  k_mlp<<<1, 256, 0, stream>>>(feats, W1e, b1e, W2e, b2e, W1u, b1u, W2u, b2u, gain, out);
}